// Round 1
// baseline (403.693 us; speedup 1.0000x reference)
//
#include <hip/hip_runtime.h>

#define B_   4
#define T_   2048
#define D_   1024
#define MTOK 8192  // B_*T_

typedef __attribute__((ext_vector_type(8))) __bf16 bf16x8;
typedef __attribute__((ext_vector_type(4))) float  f32x4;

#define GLD(G, L) __builtin_amdgcn_global_load_lds(                       \
    (const __attribute__((address_space(1))) void*)(G),                   \
    (__attribute__((address_space(3))) void*)(L), 16, 0, 0)

__device__ __forceinline__ unsigned short f2bf(float f) {
  unsigned int u = __builtin_bit_cast(unsigned int, f);
  u += 0x7fffu + ((u >> 16) & 1u);   // round-to-nearest-even
  return (unsigned short)(u >> 16);
}
__device__ __forceinline__ float bf2f(unsigned short h) {
  return __builtin_bit_cast(float, ((unsigned int)h) << 16);
}

// ---------------- prep: split x (fp32 -> hi/lo bf16) ----------------
__global__ __launch_bounds__(256) void split_x_kernel(
    const float4* __restrict__ in, ushort4* __restrict__ hi,
    ushort4* __restrict__ lo, int n4) {
  int i = blockIdx.x * 256 + threadIdx.x;
  if (i >= n4) return;
  float4 v = in[i];
  ushort4 h, l;
  h.x = f2bf(v.x); l.x = f2bf(v.x - bf2f(h.x));
  h.y = f2bf(v.y); l.y = f2bf(v.y - bf2f(h.y));
  h.z = f2bf(v.z); l.z = f2bf(v.z - bf2f(h.z));
  h.w = f2bf(v.w); l.w = f2bf(v.w - bf2f(h.w));
  hi[i] = h; lo[i] = l;
}

// ---------------- prep: transpose + split W -------------------------
__global__ __launch_bounds__(256) void wsplit_t_kernel(
    const float* __restrict__ Wq, const float* __restrict__ Wk,
    const float* __restrict__ Wv, unsigned short* __restrict__ wthi,
    unsigned short* __restrict__ wtlo) {
  __shared__ float tile[32][33];
  int z = blockIdx.z;
  const float* W = (z == 0) ? Wq : ((z == 1) ? Wk : Wv);
  int c0 = blockIdx.x * 32, r0 = blockIdx.y * 32;
  int tx = threadIdx.x & 31, ty = threadIdx.x >> 5;  // 32 x 8
  #pragma unroll
  for (int i = 0; i < 4; ++i)
    tile[ty + i * 8][tx] = W[(size_t)(r0 + ty + i * 8) * D_ + c0 + tx];
  __syncthreads();
  unsigned short* oh = wthi + (size_t)z * D_ * D_;
  unsigned short* ol = wtlo + (size_t)z * D_ * D_;
  #pragma unroll
  for (int i = 0; i < 4; ++i) {
    float v = tile[tx][ty + i * 8];
    unsigned short h = f2bf(v);
    unsigned short l = f2bf(v - bf2f(h));
    size_t idx = (size_t)(c0 + ty + i * 8) * D_ + r0 + tx;
    oh[idx] = h; ol[idx] = l;
  }
}

// ---------------- GEMM (bt-form): C[m][n] = sum_k A[m][k]*B[n][k] ---
// NPROD: 1 = plain bf16 (hi only); 3 = split hi/lo (hi*hi + hi*lo + lo*hi)
// EPI:   0 = fp32 store; 1 = split hi/lo bf16 store; 2 = bf16 transposed (Vt)
template <int NPROD, int EPI>
__global__ __launch_bounds__(256) void gemm_bt(
    const unsigned short* __restrict__ Ah, const unsigned short* __restrict__ Al,
    const unsigned short* __restrict__ Bh, const unsigned short* __restrict__ Bl,
    void* __restrict__ C0, void* __restrict__ C1,
    int M, int N, int K, long aBatch, long bBatch, long cBatch) {
  constexpr int NC = (NPROD == 3) ? 2 : 1;
  __shared__ unsigned short lsA[NC * 128 * 32];
  __shared__ unsigned short lsB[NC * 128 * 32];

  const int z = blockIdx.z;
  Ah += (size_t)z * aBatch;
  Bh += (size_t)z * bBatch;
  if constexpr (NPROD == 3) {
    Al += (size_t)z * aBatch;
    Bl += (size_t)z * bBatch;
  }
  const int tid = threadIdx.x;
  const int wid = tid >> 6, lane = tid & 63;
  const int wr = wid >> 1, wc = wid & 1;
  const int brow = blockIdx.y * 128, bcol = blockIdx.x * 128;

  f32x4 acc[4][4] = {};

  const int srow = lane >> 2;          // staging: row-within-16 per lane
  const int skq  = (lane & 3) * 8;     // staging: 8 bf16 (16B) per lane
  const int aoff = ((wr * 64) + (lane & 15)) * 32 + (lane >> 4) * 8;
  const int boff = ((wc * 64) + (lane & 15)) * 32 + (lane >> 4) * 8;

  for (int k0 = 0; k0 < K; k0 += 32) {
    #pragma unroll
    for (int i = 0; i < 2; ++i) {
      int r = i * 64 + wid * 16 + srow;
      unsigned short* dA = &lsA[i * 2048 + wid * 512];  // wave-uniform base
      unsigned short* dB = &lsB[i * 2048 + wid * 512];
      GLD(Ah + (size_t)(brow + r) * K + k0 + skq, dA);
      GLD(Bh + (size_t)(bcol + r) * K + k0 + skq, dB);
      if constexpr (NPROD == 3) {
        GLD(Al + (size_t)(brow + r) * K + k0 + skq, dA + 4096);
        GLD(Bl + (size_t)(bcol + r) * K + k0 + skq, dB + 4096);
      }
    }
    __syncthreads();

    bf16x8 ah[4], bh[4], al[4], bl[4];
    #pragma unroll
    for (int m = 0; m < 4; ++m) {
      ah[m] = *reinterpret_cast<const bf16x8*>(&lsA[aoff + m * 512]);
      if constexpr (NPROD == 3)
        al[m] = *reinterpret_cast<const bf16x8*>(&lsA[4096 + aoff + m * 512]);
    }
    #pragma unroll
    for (int n = 0; n < 4; ++n) {
      bh[n] = *reinterpret_cast<const bf16x8*>(&lsB[boff + n * 512]);
      if constexpr (NPROD == 3)
        bl[n] = *reinterpret_cast<const bf16x8*>(&lsB[4096 + boff + n * 512]);
    }
    #pragma unroll
    for (int m = 0; m < 4; ++m)
      #pragma unroll
      for (int n = 0; n < 4; ++n) {
        acc[m][n] = __builtin_amdgcn_mfma_f32_16x16x32_bf16(ah[m], bh[n], acc[m][n], 0, 0, 0);
        if constexpr (NPROD == 3) {
          acc[m][n] = __builtin_amdgcn_mfma_f32_16x16x32_bf16(ah[m], bl[n], acc[m][n], 0, 0, 0);
          acc[m][n] = __builtin_amdgcn_mfma_f32_16x16x32_bf16(al[m], bh[n], acc[m][n], 0, 0, 0);
        }
      }
    __syncthreads();
  }

  const int lrow = (lane >> 4) * 4;
  const int lcol = lane & 15;
  #pragma unroll
  for (int m = 0; m < 4; ++m)
    #pragma unroll
    for (int n = 0; n < 4; ++n)
      #pragma unroll
      for (int r = 0; r < 4; ++r) {
        int row = brow + wr * 64 + m * 16 + lrow + r;
        int col = bcol + wc * 64 + n * 16 + lcol;
        float v = acc[m][n][r];
        if constexpr (EPI == 0) {
          float* C = (float*)C0 + (size_t)z * cBatch;
          C[(size_t)row * N + col] = v;
        } else if constexpr (EPI == 1) {
          unsigned short h = f2bf(v);
          unsigned short l = f2bf(v - bf2f(h));
          ((unsigned short*)C0)[(size_t)row * N + col] = h;
          ((unsigned short*)C1)[(size_t)row * N + col] = l;
        } else {  // EPI == 2: V transposed: Vt[b][col][t]
          int b = row >> 11, t = row & 2047;
          ((unsigned short*)C0)[(size_t)b * D_ * T_ + (size_t)col * T_ + t] = f2bf(v);
        }
      }
}

// ---------------- softmax over the QUERY axis (columns) -------------
__global__ __launch_bounds__(256) void sm_pass1(const float* __restrict__ scores,
                                                float* __restrict__ pmax,
                                                float* __restrict__ psum) {
  int k = blockIdx.x * 256 + threadIdx.x;
  int qc = blockIdx.y, b = blockIdx.z;
  const float* S = scores + (size_t)b * T_ * T_ + (size_t)qc * 128 * T_ + k;
  float m = -3.0e38f, s = 0.f;
  #pragma unroll 4
  for (int q = 0; q < 128; ++q) {
    float v = S[(size_t)q * T_];
    float mn = fmaxf(m, v);
    s = s * __expf(m - mn) + __expf(v - mn);
    m = mn;
  }
  int idx = (b * 16 + qc) * T_ + k;
  pmax[idx] = m;
  psum[idx] = s;
}

__global__ __launch_bounds__(256) void sm_pass2(const float* __restrict__ pmax,
                                                const float* __restrict__ psum,
                                                float* __restrict__ stats) {
  int i = blockIdx.x * 256 + threadIdx.x;  // b*2048 + k
  int b = i >> 11, k = i & 2047;
  float M = -3.0e38f;
  #pragma unroll
  for (int qc = 0; qc < 16; ++qc) M = fmaxf(M, pmax[(b * 16 + qc) * T_ + k]);
  float S = 0.f;
  #pragma unroll
  for (int qc = 0; qc < 16; ++qc)
    S += psum[(b * 16 + qc) * T_ + k] * __expf(pmax[(b * 16 + qc) * T_ + k] - M);
  stats[2 * i] = M;
  stats[2 * i + 1] = 1.0f / S;
}

__global__ __launch_bounds__(256) void sm_pass3(const float* __restrict__ scores,
                                                const float* __restrict__ stats,
                                                unsigned short* __restrict__ wts) {
  int k = blockIdx.x * 256 + threadIdx.x;
  int qc = blockIdx.y, b = blockIdx.z;
  float M = stats[2 * (b * T_ + k)];
  float Sinv = stats[2 * (b * T_ + k) + 1];
  const float* S = scores + (size_t)b * T_ * T_ + (size_t)qc * 128 * T_ + k;
  unsigned short* W = wts + (size_t)b * T_ * T_ + (size_t)qc * 128 * T_ + k;
  #pragma unroll 4
  for (int q = 0; q < 128; ++q) {
    float v = S[(size_t)q * T_];
    W[(size_t)q * T_] = f2bf(__expf(v - M) * Sinv);
  }
}

// --------------------------------------------------------------------
extern "C" void kernel_launch(void* const* d_in, const int* in_sizes, int n_in,
                              void* d_out, int out_size, void* d_ws, size_t ws_size,
                              hipStream_t stream) {
  const float* x  = (const float*)d_in[0];
  const float* Wq = (const float*)d_in[1];
  const float* Wk = (const float*)d_in[2];
  const float* Wv = (const float*)d_in[3];
  float* out = (float*)d_out;

  char* ws = (char*)d_ws;
  const size_t MB = 1024ull * 1024ull;
  float*          scores = (float*)(ws);                      // 64 MB
  unsigned short* Qhi  = (unsigned short*)(ws + 64 * MB);     // 16 MB
  unsigned short* Qlo  = (unsigned short*)(ws + 80 * MB);     // 16 MB
  unsigned short* Khi  = (unsigned short*)(ws + 96 * MB);     // 16 MB
  unsigned short* Klo  = (unsigned short*)(ws + 112 * MB);    // 16 MB
  unsigned short* Vt   = (unsigned short*)(ws + 128 * MB);    // 16 MB
  unsigned short* xhi  = (unsigned short*)(ws + 144 * MB);    // 16 MB (dead after QKV)
  unsigned short* xlo  = (unsigned short*)(ws + 160 * MB);    // 16 MB (dead after QKV)
  unsigned short* wthi = (unsigned short*)(ws + 176 * MB);    // 6 MB
  unsigned short* wtlo = (unsigned short*)(ws + 182 * MB);    // 6 MB
  float* pmax  = (float*)(ws + 188 * MB);                     // 512 KB
  float* psum  = (float*)(ws + 188 * MB + 512 * 1024);        // 512 KB
  float* stats = (float*)(ws + 189 * MB);                     // 64 KB
  unsigned short* wts = (unsigned short*)(ws + 144 * MB);     // 32 MB, reuses x region

  // 1. split x into hi/lo bf16
  split_x_kernel<<<MTOK * D_ / 4 / 256, 256, 0, stream>>>(
      (const float4*)x, (ushort4*)xhi, (ushort4*)xlo, MTOK * D_ / 4);

  // 2. transpose + split all three W
  wsplit_t_kernel<<<dim3(32, 32, 3), 256, 0, stream>>>(Wq, Wk, Wv, wthi, wtlo);

  // 3. QKV projections (Q,K split-precision; V plain bf16 + transposed store)
  gemm_bt<3, 1><<<dim3(D_ / 128, MTOK / 128, 1), 256, 0, stream>>>(
      xhi, xlo, wthi, wtlo, Qhi, Qlo, MTOK, D_, D_, 0, 0, 0);
  gemm_bt<3, 1><<<dim3(D_ / 128, MTOK / 128, 1), 256, 0, stream>>>(
      xhi, xlo, wthi + 1048576, wtlo + 1048576, Khi, Klo, MTOK, D_, D_, 0, 0, 0);
  gemm_bt<1, 2><<<dim3(D_ / 128, MTOK / 128, 1), 256, 0, stream>>>(
      xhi, nullptr, wthi + 2097152, nullptr, Vt, nullptr, MTOK, D_, D_, 0, 0, 0);

  // 4. scores = Q K^T (split-precision, fp32 out), per batch
  gemm_bt<3, 0><<<dim3(T_ / 128, T_ / 128, B_), 256, 0, stream>>>(
      Qhi, Qlo, Khi, Klo, scores, nullptr, T_, T_, D_,
      (long)T_ * D_, (long)T_ * D_, (long)T_ * T_);

  // 5. softmax over query axis -> bf16 weights
  sm_pass1<<<dim3(8, 16, 4), 256, 0, stream>>>(scores, pmax, psum);
  sm_pass2<<<32, 256, 0, stream>>>(pmax, psum, stats);
  sm_pass3<<<dim3(8, 16, 4), 256, 0, stream>>>(scores, stats, wts);

  // 6. out = weights @ V  (bt-form against Vt)
  gemm_bt<1, 0><<<dim3(D_ / 128, T_ / 128, B_), 256, 0, stream>>>(
      wts, nullptr, Vt, nullptr, out, nullptr, T_, D_, T_,
      (long)T_ * T_, (long)D_ * T_, (long)T_ * D_);
}

// Round 2
// 276.211 us; speedup vs baseline: 1.4615x; 1.4615x over previous
//
#include <hip/hip_runtime.h>

#define B_   4
#define T_   2048
#define D_   1024
#define MTOK 8192  // B_*T_

typedef __attribute__((ext_vector_type(8))) _Float16 half8;
typedef __attribute__((ext_vector_type(4))) float    f32x4;

#define GLD(G, L) __builtin_amdgcn_global_load_lds(                       \
    (const __attribute__((address_space(1))) void*)(G),                   \
    (__attribute__((address_space(3))) void*)(L), 16, 0, 0)

__device__ __forceinline__ unsigned short f2h(float f) {
  return __builtin_bit_cast(unsigned short, (_Float16)f);  // RTE
}

// ---------------- prep: x fp32 -> fp16 ------------------------------
__global__ __launch_bounds__(256) void tofp16_kernel(
    const float4* __restrict__ in, ushort4* __restrict__ out, int n4) {
  int i = blockIdx.x * 256 + threadIdx.x;
  if (i >= n4) return;
  float4 v = in[i];
  ushort4 h;
  h.x = f2h(v.x); h.y = f2h(v.y); h.z = f2h(v.z); h.w = f2h(v.w);
  out[i] = h;
}

// ---------------- prep: transpose + concat W -> fp16 ----------------
// Wt[3072][1024]: row n = output-dim n of (Wq|Wk|Wv), contiguous in d.
__global__ __launch_bounds__(256) void wcat_t_kernel(
    const float* __restrict__ Wq, const float* __restrict__ Wk,
    const float* __restrict__ Wv, unsigned short* __restrict__ Wt) {
  __shared__ float tile[32][33];
  int z = blockIdx.z;
  const float* W = (z == 0) ? Wq : ((z == 1) ? Wk : Wv);
  int c0 = blockIdx.x * 32, r0 = blockIdx.y * 32;
  int tx = threadIdx.x & 31, ty = threadIdx.x >> 5;  // 32 x 8
  #pragma unroll
  for (int i = 0; i < 4; ++i)
    tile[ty + i * 8][tx] = W[(size_t)(r0 + ty + i * 8) * D_ + c0 + tx];
  __syncthreads();
  #pragma unroll
  for (int i = 0; i < 4; ++i) {
    float v = tile[tx][ty + i * 8];
    size_t row = (size_t)z * D_ + c0 + ty + i * 8;
    Wt[row * D_ + r0 + tx] = f2h(v);
  }
}

// ---------------- GEMM (bt-form, fp16): C[m][n] = sum_k A[m][k]B[n][k]
// EPI: 0 = fp32 store to C0; 1 = QKV epilogue (fp16: cols<2048 -> QK
//      row-major ldc=2048, cols>=2048 -> Vt[b][d][t])
template <int EPI>
__global__ __launch_bounds__(256) void gemm_f16(
    const unsigned short* __restrict__ A, const unsigned short* __restrict__ B,
    void* __restrict__ C0, void* __restrict__ C1,
    int M, int N, int K, int lda, int ldb, int ldc,
    long aBatch, long bBatch, long cBatch) {
  __shared__ unsigned short lsA[128 * 32];
  __shared__ unsigned short lsB[128 * 32];

  const int z = blockIdx.z;
  A += (size_t)z * aBatch;
  B += (size_t)z * bBatch;

  const int tid = threadIdx.x;
  const int wid = tid >> 6, lane = tid & 63;
  const int wr = wid >> 1, wc = wid & 1;
  const int brow = blockIdx.y * 128, bcol = blockIdx.x * 128;

  f32x4 acc[4][4] = {};

  const int srow = lane >> 2;          // staging: row-within-16 per lane
  const int skq  = (lane & 3) * 8;     // staging: 8 fp16 (16B) per lane
  const int aoff = ((wr * 64) + (lane & 15)) * 32 + (lane >> 4) * 8;
  const int boff = ((wc * 64) + (lane & 15)) * 32 + (lane >> 4) * 8;

  for (int k0 = 0; k0 < K; k0 += 32) {
    #pragma unroll
    for (int i = 0; i < 2; ++i) {
      int r = i * 64 + wid * 16 + srow;
      unsigned short* dA = &lsA[i * 2048 + wid * 512];  // wave-uniform base
      unsigned short* dB = &lsB[i * 2048 + wid * 512];
      GLD(A + (size_t)(brow + r) * lda + k0 + skq, dA);
      GLD(B + (size_t)(bcol + r) * ldb + k0 + skq, dB);
    }
    __syncthreads();

    half8 ah[4], bh[4];
    #pragma unroll
    for (int m = 0; m < 4; ++m)
      ah[m] = *reinterpret_cast<const half8*>(&lsA[aoff + m * 512]);
    #pragma unroll
    for (int n = 0; n < 4; ++n)
      bh[n] = *reinterpret_cast<const half8*>(&lsB[boff + n * 512]);

    #pragma unroll
    for (int m = 0; m < 4; ++m)
      #pragma unroll
      for (int n = 0; n < 4; ++n)
        acc[m][n] = __builtin_amdgcn_mfma_f32_16x16x32_f16(ah[m], bh[n], acc[m][n], 0, 0, 0);
    __syncthreads();
  }

  const int lrow = (lane >> 4) * 4;
  const int lcol = lane & 15;
  #pragma unroll
  for (int m = 0; m < 4; ++m)
    #pragma unroll
    for (int n = 0; n < 4; ++n)
      #pragma unroll
      for (int r = 0; r < 4; ++r) {
        int row = brow + wr * 64 + m * 16 + lrow + r;
        int col = bcol + wc * 64 + n * 16 + lcol;
        float v = acc[m][n][r];
        if constexpr (EPI == 0) {
          float* C = (float*)C0 + (size_t)z * cBatch;
          C[(size_t)row * ldc + col] = v;
        } else {  // EPI == 1: QKV mixed epilogue
          unsigned short h = f2h(v);
          if (col < 2048) {
            ((unsigned short*)C0)[(size_t)row * 2048 + col] = h;
          } else {
            int b = row >> 11, t = row & 2047;
            ((unsigned short*)C1)[((size_t)b * D_ + (col - 2048)) * T_ + t] = h;
          }
        }
      }
}

// ---------------- softmax over the QUERY axis (columns) -------------
__global__ __launch_bounds__(256) void sm_pass1(const float* __restrict__ scores,
                                                float* __restrict__ pmax,
                                                float* __restrict__ psum) {
  int k = blockIdx.x * 256 + threadIdx.x;
  int qc = blockIdx.y, b = blockIdx.z;
  const float* S = scores + (size_t)b * T_ * T_ + (size_t)qc * 128 * T_ + k;
  float m = -3.0e38f, s = 0.f;
  #pragma unroll 4
  for (int q = 0; q < 128; ++q) {
    float v = S[(size_t)q * T_];
    float mn = fmaxf(m, v);
    s = s * __expf(m - mn) + __expf(v - mn);
    m = mn;
  }
  int idx = (b * 16 + qc) * T_ + k;
  pmax[idx] = m;
  psum[idx] = s;
}

__global__ __launch_bounds__(256) void sm_pass2(const float* __restrict__ pmax,
                                                const float* __restrict__ psum,
                                                float* __restrict__ stats) {
  int i = blockIdx.x * 256 + threadIdx.x;  // b*2048 + k
  int b = i >> 11, k = i & 2047;
  float M = -3.0e38f;
  #pragma unroll
  for (int qc = 0; qc < 16; ++qc) M = fmaxf(M, pmax[(b * 16 + qc) * T_ + k]);
  float S = 0.f;
  #pragma unroll
  for (int qc = 0; qc < 16; ++qc)
    S += psum[(b * 16 + qc) * T_ + k] * __expf(pmax[(b * 16 + qc) * T_ + k] - M);
  stats[2 * i] = M;
  stats[2 * i + 1] = 1.0f / S;
}

__global__ __launch_bounds__(256) void sm_pass3(const float* __restrict__ scores,
                                                const float* __restrict__ stats,
                                                unsigned short* __restrict__ wts) {
  int k = blockIdx.x * 256 + threadIdx.x;
  int qc = blockIdx.y, b = blockIdx.z;
  float M = stats[2 * (b * T_ + k)];
  float Sinv = stats[2 * (b * T_ + k) + 1];
  const float* S = scores + (size_t)b * T_ * T_ + (size_t)qc * 128 * T_ + k;
  unsigned short* W = wts + (size_t)b * T_ * T_ + (size_t)qc * 128 * T_ + k;
  #pragma unroll 4
  for (int q = 0; q < 128; ++q) {
    float v = S[(size_t)q * T_];
    W[(size_t)q * T_] = f2h(__expf(v - M) * Sinv);
  }
}

// --------------------------------------------------------------------
extern "C" void kernel_launch(void* const* d_in, const int* in_sizes, int n_in,
                              void* d_out, int out_size, void* d_ws, size_t ws_size,
                              hipStream_t stream) {
  const float* x  = (const float*)d_in[0];
  const float* Wq = (const float*)d_in[1];
  const float* Wk = (const float*)d_in[2];
  const float* Wv = (const float*)d_in[3];
  float* out = (float*)d_out;

  char* ws = (char*)d_ws;
  const size_t MB = 1024ull * 1024ull;
  float*          scores = (float*)(ws);                       // 64 MB
  unsigned short* QK   = (unsigned short*)(ws + 64 * MB);      // 32 MB [8192][2048]
  unsigned short* Vt   = (unsigned short*)(ws + 96 * MB);      // 16 MB [4][1024][2048]
  unsigned short* xh   = (unsigned short*)(ws + 112 * MB);     // 16 MB fp16 x
  unsigned short* Wt   = (unsigned short*)(ws + 128 * MB);     // 6 MB  [3072][1024]
  float* pmax  = (float*)(ws + 134 * MB);                      // 512 KB
  float* psum  = (float*)(ws + 134 * MB + 512 * 1024);         // 512 KB
  float* stats = (float*)(ws + 135 * MB);                      // 64 KB
  unsigned short* wts = (unsigned short*)(ws + 136 * MB);      // 32 MB fp16

  // 1. x -> fp16
  tofp16_kernel<<<MTOK * D_ / 4 / 256, 256, 0, stream>>>(
      (const float4*)x, (ushort4*)xh, MTOK * D_ / 4);

  // 2. transpose + concat W -> fp16
  wcat_t_kernel<<<dim3(32, 32, 3), 256, 0, stream>>>(Wq, Wk, Wv, Wt);

  // 3. fused QKV projection (fp16): C[8192][3072]; V stored transposed
  gemm_f16<1><<<dim3(3072 / 128, MTOK / 128, 1), 256, 0, stream>>>(
      xh, Wt, QK, Vt, MTOK, 3072, D_, D_, D_, 0, 0, 0, 0);

  // 4. scores = Q K^T (fp16 in, fp32 out), per batch
  gemm_f16<0><<<dim3(T_ / 128, T_ / 128, B_), 256, 0, stream>>>(
      QK, QK + 1024, scores, nullptr, T_, T_, D_, 2048, 2048, T_,
      (long)T_ * 2048, (long)T_ * 2048, (long)T_ * T_);

  // 5. softmax over query axis -> fp16 weights
  sm_pass1<<<dim3(8, 16, 4), 256, 0, stream>>>(scores, pmax, psum);
  sm_pass2<<<32, 256, 0, stream>>>(pmax, psum, stats);
  sm_pass3<<<dim3(8, 16, 4), 256, 0, stream>>>(scores, stats, wts);

  // 6. out = weights @ V  (fp16, bt-form against Vt)
  gemm_f16<0><<<dim3(D_ / 128, T_ / 128, B_), 256, 0, stream>>>(
      wts, Vt, out, nullptr, T_, D_, T_, T_, T_, D_,
      (long)T_ * T_, (long)D_ * T_, (long)T_ * D_);
}

// Round 3
// 230.020 us; speedup vs baseline: 1.7550x; 1.2008x over previous
//
#include <hip/hip_runtime.h>

#define B_   4
#define T_   2048
#define D_   1024
#define MTOK 8192  // B_*T_

typedef __attribute__((ext_vector_type(8))) _Float16 half8;
typedef __attribute__((ext_vector_type(4))) float    f32x4;

#define GLD(G, L) __builtin_amdgcn_global_load_lds(                       \
    (const __attribute__((address_space(1))) void*)(G),                   \
    (__attribute__((address_space(3))) void*)(L), 16, 0, 0)

__device__ __forceinline__ unsigned short f2h(float f) {
  return __builtin_bit_cast(unsigned short, (_Float16)f);  // RTE
}

// ---------------- prep: x fp32 -> fp16 ------------------------------
__global__ __launch_bounds__(256) void tofp16_kernel(
    const float4* __restrict__ in, ushort4* __restrict__ out, int n4) {
  int i = blockIdx.x * 256 + threadIdx.x;
  if (i >= n4) return;
  float4 v = in[i];
  ushort4 h;
  h.x = f2h(v.x); h.y = f2h(v.y); h.z = f2h(v.z); h.w = f2h(v.w);
  out[i] = h;
}

// ---------------- prep: transpose + concat W -> fp16 ----------------
__global__ __launch_bounds__(256) void wcat_t_kernel(
    const float* __restrict__ Wq, const float* __restrict__ Wk,
    const float* __restrict__ Wv, unsigned short* __restrict__ Wt) {
  __shared__ float tile[32][33];
  int z = blockIdx.z;
  const float* W = (z == 0) ? Wq : ((z == 1) ? Wk : Wv);
  int c0 = blockIdx.x * 32, r0 = blockIdx.y * 32;
  int tx = threadIdx.x & 31, ty = threadIdx.x >> 5;  // 32 x 8
  #pragma unroll
  for (int i = 0; i < 4; ++i)
    tile[ty + i * 8][tx] = W[(size_t)(r0 + ty + i * 8) * D_ + c0 + tx];
  __syncthreads();
  #pragma unroll
  for (int i = 0; i < 4; ++i) {
    float v = tile[tx][ty + i * 8];
    size_t row = (size_t)z * D_ + c0 + ty + i * 8;
    Wt[row * D_ + r0 + tx] = f2h(v);
  }
}

// ---------------- pipelined GEMM (bt-form, fp16) --------------------
// C[m][n] = sum_k A[m][k] * B[n][k].  BM=128, BN=256, BK=32, 512 thr.
// 3 LDS buffers, staged 2 K-tiles ahead, counted vmcnt(3), 1 barrier/tile.
// EPI: 0 = fp32 store; 1 = QKV epilogue (col<2048 -> QK, else Vt[b][d][t])
template <int EPI>
__global__ __launch_bounds__(512) void gemm2(
    const unsigned short* __restrict__ A, const unsigned short* __restrict__ B,
    void* __restrict__ C0, void* __restrict__ C1,
    int N, int K, int lda, int ldb, int ldc,
    long aBatch, long bBatch, long cBatch) {
  // per buffer: A 8192 B + B 16384 B = 24576 B; 3 buffers = 72 KB
  __shared__ char lds[3 * 24576];

  const int z = blockIdx.z;
  A += (size_t)z * aBatch;
  B += (size_t)z * bBatch;

  const int tid = threadIdx.x;
  const int wid = tid >> 6, lane = tid & 63;
  const int wr = wid >> 2, wc = wid & 3;           // 2 x 4 wave grid
  const int brow = blockIdx.y * 128, bcol = blockIdx.x * 256;

  // ---- staging geometry (write side; rule #21: inverse-swz source) ----
  // linear LDS dest rows: rowA = wid*16 + lane/4, physical slot = lane&3
  // swizzle key = ((row>>1)&3) = (lane>>3)&3  (row offsets are mult of 16)
  const int rowA  = wid * 16 + (lane >> 2);
  const int wslot = (lane & 3) ^ ((lane >> 3) & 3);
  const unsigned short* srcA  = A + (size_t)(brow + rowA) * lda + wslot * 8;
  const unsigned short* srcB0 = B + (size_t)(bcol + rowA) * ldb + wslot * 8;
  const unsigned short* srcB1 = B + (size_t)(bcol + 128 + rowA) * ldb + wslot * 8;

  // ---- read geometry (swizzled): key = (lane>>1)&3 (frag bases mult 16)
  const int rdslot = ((lane >> 4) ^ ((lane >> 1) & 3)) * 16;
  const int aRd = (wr * 64 + (lane & 15)) * 64 + rdslot;          // +m*1024
  const int bRd = 8192 + (wc * 64 + (lane & 15)) * 64 + rdslot;   // +n*1024

  f32x4 acc[4][4] = {};
  const int nT = K / 32;

  // prologue: stage tiles 0 and 1
  #pragma unroll
  for (int p = 0; p < 2; ++p) {
    char* db = lds + p * 24576 + wid * 1024;
    GLD(srcA, db);
    GLD(srcB0, db + 8192);
    GLD(srcB1, db + 16384);
    srcA += 32; srcB0 += 32; srcB1 += 32;
  }

  int buf = 0, sbuf = 2;
  for (int t = 0; t < nT; ++t) {
    if (t + 2 < nT)
      asm volatile("s_waitcnt vmcnt(3)\n\ts_barrier" ::: "memory");
    else
      asm volatile("s_waitcnt vmcnt(0)\n\ts_barrier" ::: "memory");

    const char* la = lds + buf * 24576;
    half8 ah[4], bh[4];
    #pragma unroll
    for (int m = 0; m < 4; ++m)
      ah[m] = *(const half8*)(la + aRd + m * 1024);
    #pragma unroll
    for (int n = 0; n < 4; ++n)
      bh[n] = *(const half8*)(la + bRd + n * 1024);

    if (t + 2 < nT) {  // stage tile t+2 into buffer read by tile t-1
      char* db = lds + sbuf * 24576 + wid * 1024;
      GLD(srcA, db);
      GLD(srcB0, db + 8192);
      GLD(srcB1, db + 16384);
      srcA += 32; srcB0 += 32; srcB1 += 32;
    }

    __builtin_amdgcn_s_setprio(1);
    #pragma unroll
    for (int m = 0; m < 4; ++m)
      #pragma unroll
      for (int n = 0; n < 4; ++n)
        acc[m][n] = __builtin_amdgcn_mfma_f32_16x16x32_f16(ah[m], bh[n], acc[m][n], 0, 0, 0);
    __builtin_amdgcn_s_setprio(0);

    buf  = (buf == 2)  ? 0 : buf + 1;
    sbuf = (sbuf == 2) ? 0 : sbuf + 1;
  }

  const int lrow = (lane >> 4) * 4;
  const int lcol = lane & 15;
  #pragma unroll
  for (int m = 0; m < 4; ++m)
    #pragma unroll
    for (int n = 0; n < 4; ++n)
      #pragma unroll
      for (int r = 0; r < 4; ++r) {
        int row = brow + wr * 64 + m * 16 + lrow + r;
        int col = bcol + wc * 64 + n * 16 + lcol;
        float v = acc[m][n][r];
        if constexpr (EPI == 0) {
          float* C = (float*)C0 + (size_t)z * cBatch;
          C[(size_t)row * ldc + col] = v;
        } else {  // QKV mixed epilogue
          unsigned short h = f2h(v);
          if (col < 2048) {
            ((unsigned short*)C0)[(size_t)row * 2048 + col] = h;
          } else {
            int b = row >> 11, tt = row & 2047;
            ((unsigned short*)C1)[((size_t)b * D_ + (col - 2048)) * T_ + tt] = h;
          }
        }
      }
}

// ---------------- softmax over the QUERY axis (columns) -------------
__global__ __launch_bounds__(256) void sm_pass1(const float* __restrict__ scores,
                                                float* __restrict__ pmax,
                                                float* __restrict__ psum) {
  int k = blockIdx.x * 256 + threadIdx.x;
  int qc = blockIdx.y, b = blockIdx.z;
  const float* S = scores + (size_t)b * T_ * T_ + (size_t)qc * 128 * T_ + k;
  float m = -3.0e38f, s = 0.f;
  #pragma unroll 4
  for (int q = 0; q < 128; ++q) {
    float v = S[(size_t)q * T_];
    float mn = fmaxf(m, v);
    s = s * __expf(m - mn) + __expf(v - mn);
    m = mn;
  }
  int idx = (b * 16 + qc) * T_ + k;
  pmax[idx] = m;
  psum[idx] = s;
}

__global__ __launch_bounds__(256) void sm_pass2(const float* __restrict__ pmax,
                                                const float* __restrict__ psum,
                                                float* __restrict__ stats) {
  int i = blockIdx.x * 256 + threadIdx.x;  // b*2048 + k
  int b = i >> 11, k = i & 2047;
  float M = -3.0e38f;
  #pragma unroll
  for (int qc = 0; qc < 16; ++qc) M = fmaxf(M, pmax[(b * 16 + qc) * T_ + k]);
  float S = 0.f;
  #pragma unroll
  for (int qc = 0; qc < 16; ++qc)
    S += psum[(b * 16 + qc) * T_ + k] * __expf(pmax[(b * 16 + qc) * T_ + k] - M);
  stats[2 * i] = M;
  stats[2 * i + 1] = 1.0f / S;
}

__global__ __launch_bounds__(256) void sm_pass3(const float* __restrict__ scores,
                                                const float* __restrict__ stats,
                                                unsigned short* __restrict__ wts) {
  int k = blockIdx.x * 256 + threadIdx.x;
  int qc = blockIdx.y, b = blockIdx.z;
  float M = stats[2 * (b * T_ + k)];
  float Sinv = stats[2 * (b * T_ + k) + 1];
  const float* S = scores + (size_t)b * T_ * T_ + (size_t)qc * 128 * T_ + k;
  unsigned short* W = wts + (size_t)b * T_ * T_ + (size_t)qc * 128 * T_ + k;
  #pragma unroll 4
  for (int q = 0; q < 128; ++q) {
    float v = S[(size_t)q * T_];
    W[(size_t)q * T_] = f2h(__expf(v - M) * Sinv);
  }
}

// --------------------------------------------------------------------
extern "C" void kernel_launch(void* const* d_in, const int* in_sizes, int n_in,
                              void* d_out, int out_size, void* d_ws, size_t ws_size,
                              hipStream_t stream) {
  const float* x  = (const float*)d_in[0];
  const float* Wq = (const float*)d_in[1];
  const float* Wk = (const float*)d_in[2];
  const float* Wv = (const float*)d_in[3];
  float* out = (float*)d_out;

  char* ws = (char*)d_ws;
  const size_t MB = 1024ull * 1024ull;
  float*          scores = (float*)(ws);                       // 64 MB
  unsigned short* QK   = (unsigned short*)(ws + 64 * MB);      // 32 MB [8192][2048]
  unsigned short* Vt   = (unsigned short*)(ws + 96 * MB);      // 16 MB [4][1024][2048]
  unsigned short* xh   = (unsigned short*)(ws + 112 * MB);     // 16 MB fp16 x
  unsigned short* Wt   = (unsigned short*)(ws + 128 * MB);     // 6 MB  [3072][1024]
  float* pmax  = (float*)(ws + 134 * MB);                      // 512 KB
  float* psum  = (float*)(ws + 134 * MB + 512 * 1024);         // 512 KB
  float* stats = (float*)(ws + 135 * MB);                      // 64 KB
  unsigned short* wts = (unsigned short*)(ws + 136 * MB);      // 32 MB fp16

  // 1. x -> fp16
  tofp16_kernel<<<MTOK * D_ / 4 / 256, 256, 0, stream>>>(
      (const float4*)x, (ushort4*)xh, MTOK * D_ / 4);

  // 2. transpose + concat W -> fp16
  wcat_t_kernel<<<dim3(32, 32, 3), 256, 0, stream>>>(Wq, Wk, Wv, Wt);

  // 3. fused QKV projection: C[8192][3072]; V stored transposed
  gemm2<1><<<dim3(3072 / 256, MTOK / 128, 1), 512, 0, stream>>>(
      xh, Wt, QK, Vt, 3072, D_, D_, D_, 0, 0, 0, 0);

  // 4. scores = Q K^T (fp16 in, fp32 out), per batch
  gemm2<0><<<dim3(T_ / 256, T_ / 128, B_), 512, 0, stream>>>(
      QK, QK + 1024, scores, nullptr, T_, D_, 2048, 2048, T_,
      (long)T_ * 2048, (long)T_ * 2048, (long)T_ * T_);

  // 5. softmax over query axis -> fp16 weights
  sm_pass1<<<dim3(8, 16, 4), 256, 0, stream>>>(scores, pmax, psum);
  sm_pass2<<<32, 256, 0, stream>>>(pmax, psum, stats);
  sm_pass3<<<dim3(8, 16, 4), 256, 0, stream>>>(scores, stats, wts);

  // 6. out = weights @ V  (bt-form against Vt)
  gemm2<0><<<dim3(D_ / 256, T_ / 128, B_), 512, 0, stream>>>(
      wts, Vt, out, nullptr, D_, T_, T_, T_, D_,
      (long)T_ * T_, (long)D_ * T_, (long)T_ * D_);
}

// Round 4
// 227.174 us; speedup vs baseline: 1.7770x; 1.0125x over previous
//
#include <hip/hip_runtime.h>

#define B_   4
#define T_   2048
#define D_   1024
#define MTOK 8192  // B_*T_

typedef __attribute__((ext_vector_type(8))) _Float16 half8;
typedef __attribute__((ext_vector_type(4))) float    f32x4;

#define GLD(G, L) __builtin_amdgcn_global_load_lds(                       \
    (const __attribute__((address_space(1))) void*)(G),                   \
    (__attribute__((address_space(3))) void*)(L), 16, 0, 0)

#define BAR()   __builtin_amdgcn_s_barrier()
#define LGKM0() do { asm volatile("s_waitcnt lgkmcnt(0)" ::: "memory");   \
                     __builtin_amdgcn_sched_barrier(0); } while (0)
#define VMW8()  asm volatile("s_waitcnt vmcnt(8)" ::: "memory")
#define VMW6()  asm volatile("s_waitcnt vmcnt(6)" ::: "memory")
#define VMW0()  asm volatile("s_waitcnt vmcnt(0)" ::: "memory")

__device__ __forceinline__ unsigned short f2h(float f) {
  return __builtin_bit_cast(unsigned short, (_Float16)f);  // RTE
}

// ---------------- prep: x fp32 -> fp16 ------------------------------
__global__ __launch_bounds__(256) void tofp16_kernel(
    const float4* __restrict__ in, ushort4* __restrict__ out, int n4) {
  int i = blockIdx.x * 256 + threadIdx.x;
  if (i >= n4) return;
  float4 v = in[i];
  ushort4 h;
  h.x = f2h(v.x); h.y = f2h(v.y); h.z = f2h(v.z); h.w = f2h(v.w);
  out[i] = h;
}

// ---------------- prep: transpose + concat W -> fp16 ----------------
__global__ __launch_bounds__(256) void wcat_t_kernel(
    const float* __restrict__ Wq, const float* __restrict__ Wk,
    const float* __restrict__ Wv, unsigned short* __restrict__ Wt) {
  __shared__ float tile[32][33];
  int z = blockIdx.z;
  const float* W = (z == 0) ? Wq : ((z == 1) ? Wk : Wv);
  int c0 = blockIdx.x * 32, r0 = blockIdx.y * 32;
  int tx = threadIdx.x & 31, ty = threadIdx.x >> 5;  // 32 x 8
  #pragma unroll
  for (int i = 0; i < 4; ++i)
    tile[ty + i * 8][tx] = W[(size_t)(r0 + ty + i * 8) * D_ + c0 + tx];
  __syncthreads();
  #pragma unroll
  for (int i = 0; i < 4; ++i) {
    float v = tile[tx][ty + i * 8];
    size_t row = (size_t)z * D_ + c0 + ty + i * 8;
    Wt[row * D_ + r0 + tx] = f2h(v);
  }
}

// ---------------- 8-phase pipelined GEMM (bt-form, fp16) ------------
// C[m][n] = sum_k A[m][k] * B[n][k].  BM = FM*32 (256 or 128), BN = 256,
// BK = 64, 512 threads = 8 waves (2M x 4N).  LDS: 2 K-tile buffers, each
// A[BM][64] + B[256][64] fp16, XOR-swizzled 16B slots (slot ^= row&7).
// Per K-tile: 4 phases (quadrants A0B0, A0B1, A1B1, A1B0); freed regions
// restaged next phase; counted vmcnt at phases 4/8 only.
// EPI: 0 = fp32 store; 1 = QKV epilogue (col<2048 -> QK, else Vt[b][d][t])
template <int FM, int EPI>
__global__ __launch_bounds__(512) void gemm8p(
    const unsigned short* __restrict__ A, const unsigned short* __restrict__ B,
    void* __restrict__ C0, void* __restrict__ C1,
    int K, int lda, int ldb, int ldc,
    long aBatch, long bBatch, long cBatch) {
  constexpr int BM   = FM * 32;
  constexpr int ABY  = BM * 128;        // A bytes per buffer
  constexpr int BUFB = ABY + 32768;     // bytes per K-tile buffer
  __shared__ __align__(16) char lds[2 * BUFB];

  const int z = blockIdx.z;
  A += (size_t)z * aBatch;
  B += (size_t)z * bBatch;

  // XCD-bijective swizzle (all grids have nwg % 8 == 0)
  const int nwg = gridDim.x * gridDim.y;
  int s = blockIdx.y * gridDim.x + blockIdx.x;
  s = (s & 7) * (nwg >> 3) + (s >> 3);
  const int bx = s % gridDim.x, by = s / gridDim.x;
  const int brow = by * BM, bcol = bx * 256;

  const int tid = threadIdx.x;
  const int wid = tid >> 6, lane = tid & 63;
  const int wr = wid >> 2, wc = wid & 3;
  const int l15 = lane & 15, l7 = lane & 7, g4 = lane >> 4, lr8 = lane >> 3;

  // ---- staging geometry (write side: linear LDS, inverse-swz source) ----
  const int scol = (l7 ^ lr8) * 8;  // swizzled 16B k-slot in global source
  int aoffs[2][2], adst[2][2], boffs[2][2], bdst[2][2];
  #pragma unroll
  for (int rg = 0; rg < 2; ++rg)
    #pragma unroll
    for (int j = 0; j < 2; ++j) {
      int r0;
      if constexpr (FM == 8) r0 = rg * 64 + j * 128 + wid * 8;
      else                   r0 = (wid >> 2) * 64 + rg * 32 + (wid & 3) * 8;
      aoffs[rg][j] = (brow + r0 + lr8) * lda + scol;
      adst[rg][j]  = r0 * 128;
      int g16 = j * 8 + wid;
      int rb  = (g16 >> 2) * 64 + rg * 32 + (g16 & 3) * 8;
      boffs[rg][j] = (bcol + rb + lr8) * ldb + scol;
      bdst[rg][j]  = ABY + rb * 128;
    }

  // ---- read geometry (swizzled ds_read_b128 bases) ----
  int aRd[2][2], bRd[2][2];
  #pragma unroll
  for (int mh = 0; mh < 2; ++mh)
    #pragma unroll
    for (int ks = 0; ks < 2; ++ks) {
      int arow = wr * (BM / 2) + mh * (BM / 4) + l15;
      int bcolr = wc * 64 + mh * 32 + l15;   // mh doubles as nh
      int ph = ((ks * 4) + g4) ^ l7;
      aRd[mh][ks] = arow * 128 + ph * 16;
      bRd[mh][ks] = ABY + bcolr * 128 + ph * 16;
    }

#define STAGE_A(rg, bb, tt) do {                                              \
    GLD(A + (size_t)(aoffs[rg][0] + (tt) * 64), lds + (bb) * BUFB + adst[rg][0]); \
    if constexpr (FM == 8)                                                    \
      GLD(A + (size_t)(aoffs[rg][1] + (tt) * 64), lds + (bb) * BUFB + adst[rg][1]); \
  } while (0)
#define STAGE_B(nh, bb, tt) do {                                              \
    GLD(B + (size_t)(boffs[nh][0] + (tt) * 64), lds + (bb) * BUFB + bdst[nh][0]); \
    GLD(B + (size_t)(boffs[nh][1] + (tt) * 64), lds + (bb) * BUFB + bdst[nh][1]); \
  } while (0)
#define LOAD_A(mh) do { _Pragma("unroll")                                     \
    for (int mf = 0; mf < FM / 2; ++mf) {                                     \
      ar[mf][0] = *(const half8*)(buf + aRd[mh][0] + mf * 2048);              \
      ar[mf][1] = *(const half8*)(buf + aRd[mh][1] + mf * 2048); } } while (0)
#define LOAD_B(dst, nh) do { _Pragma("unroll")                                \
    for (int nf = 0; nf < 2; ++nf) {                                          \
      dst[nf][0] = *(const half8*)(buf + bRd[nh][0] + nf * 2048);             \
      dst[nf][1] = *(const half8*)(buf + bRd[nh][1] + nf * 2048); } } while (0)
#define MFMA_Q(mh, nh, br) do { _Pragma("unroll")                             \
    for (int mf = 0; mf < FM / 2; ++mf) { _Pragma("unroll")                   \
      for (int nf = 0; nf < 2; ++nf) {                                        \
        f32x4& ac = acc[(mh) * (FM / 2) + mf][(nh) * 2 + nf];                 \
        ac = __builtin_amdgcn_mfma_f32_16x16x32_f16(ar[mf][0], br[nf][0], ac, 0, 0, 0); \
        ac = __builtin_amdgcn_mfma_f32_16x16x32_f16(ar[mf][1], br[nf][1], ac, 0, 0, 0); \
      } } } while (0)
#define VMCNT_STEADY() do { if (st) { if constexpr (FM == 8) VMW8(); else VMW6(); } \
                            else VMW0(); } while (0)

  // ---- prologue: stage K-tiles 0 (buf0) and 1 (buf1) ----
  STAGE_A(0, 0, 0); STAGE_B(0, 0, 0); STAGE_B(1, 0, 0); STAGE_A(1, 0, 0);
  STAGE_A(0, 1, 1); STAGE_B(0, 1, 1); STAGE_B(1, 1, 1); STAGE_A(1, 1, 1);
  if constexpr (FM == 8) VMW8(); else VMW6();
  BAR();

  f32x4 acc[FM][4] = {};
  half8 ar[FM / 2][2], b0r[2][2], b1r[2][2];
  const int nIter = K / 128;

  for (int it = 0; it < nIter; ++it) {
    const bool st = (it + 1 < nIter);
    #pragma unroll
    for (int h = 0; h < 2; ++h) {
      const char* buf = lds + h * BUFB;
      const int tt = 2 * it + 2 + h;
      // phase 1: read A-mh0 + B-nh0
      LOAD_A(0); LOAD_B(b0r, 0);
      BAR(); LGKM0();
      __builtin_amdgcn_s_setprio(1); MFMA_Q(0, 0, b0r);
      __builtin_amdgcn_s_setprio(0); BAR();
      // phase 2: read B-nh1; stage A0 + B0 regions (freed in phase 1)
      LOAD_B(b1r, 1);
      if (st) { STAGE_A(0, h, tt); STAGE_B(0, h, tt); }
      BAR(); LGKM0();
      __builtin_amdgcn_s_setprio(1); MFMA_Q(0, 1, b1r);
      __builtin_amdgcn_s_setprio(0); BAR();
      // phase 3: read A-mh1; stage B1 region (freed in phase 2)
      LOAD_A(1);
      if (st) STAGE_B(1, h, tt);
      BAR(); LGKM0();
      __builtin_amdgcn_s_setprio(1); MFMA_Q(1, 1, b1r);
      __builtin_amdgcn_s_setprio(0); BAR();
      // phase 4: stage A1 region (freed in phase 3); counted vmcnt
      if (st) STAGE_A(1, h, tt);
      BAR();
      __builtin_amdgcn_s_setprio(1); MFMA_Q(1, 0, b0r);
      __builtin_amdgcn_s_setprio(0);
      VMCNT_STEADY(); BAR();
    }
  }

  // ---- epilogue ----
  #pragma unroll
  for (int m = 0; m < FM; ++m) {
    int rowoff;
    if constexpr (FM == 8) rowoff = (m >> 2) * 64 + (m & 3) * 16;
    else                   rowoff = (m >> 1) * 32 + (m & 1) * 16;
    #pragma unroll
    for (int n = 0; n < 4; ++n) {
      int coloff = (n >> 1) * 32 + (n & 1) * 16;
      #pragma unroll
      for (int r = 0; r < 4; ++r) {
        int row = brow + wr * (BM / 2) + rowoff + g4 * 4 + r;
        int col = bcol + wc * 64 + coloff + l15;
        float v = acc[m][n][r];
        if constexpr (EPI == 0) {
          float* C = (float*)C0 + (size_t)z * cBatch;
          C[(size_t)row * ldc + col] = v;
        } else {
          unsigned short hh = f2h(v);
          if (col < 2048) {
            ((unsigned short*)C0)[(size_t)row * 2048 + col] = hh;
          } else {
            int b = row >> 11, t = row & 2047;
            ((unsigned short*)C1)[((size_t)b * D_ + (col - 2048)) * T_ + t] = hh;
          }
        }
      }
    }
  }
#undef STAGE_A
#undef STAGE_B
#undef LOAD_A
#undef LOAD_B
#undef MFMA_Q
#undef VMCNT_STEADY
}

// ---------------- softmax over the QUERY axis (columns) -------------
__global__ __launch_bounds__(256) void sm_pass1(const float* __restrict__ scores,
                                                float* __restrict__ pmax,
                                                float* __restrict__ psum) {
  int k = blockIdx.x * 256 + threadIdx.x;
  int qc = blockIdx.y, b = blockIdx.z;
  const float* S = scores + (size_t)b * T_ * T_ + (size_t)qc * 128 * T_ + k;
  float m = -3.0e38f, s = 0.f;
  #pragma unroll 4
  for (int q = 0; q < 128; ++q) {
    float v = S[(size_t)q * T_];
    float mn = fmaxf(m, v);
    s = s * __expf(m - mn) + __expf(v - mn);
    m = mn;
  }
  int idx = (b * 16 + qc) * T_ + k;
  pmax[idx] = m;
  psum[idx] = s;
}

__global__ __launch_bounds__(256) void sm_pass2(const float* __restrict__ pmax,
                                                const float* __restrict__ psum,
                                                float* __restrict__ stats) {
  int i = blockIdx.x * 256 + threadIdx.x;  // b*2048 + k
  int b = i >> 11, k = i & 2047;
  float M = -3.0e38f;
  #pragma unroll
  for (int qc = 0; qc < 16; ++qc) M = fmaxf(M, pmax[(b * 16 + qc) * T_ + k]);
  float S = 0.f;
  #pragma unroll
  for (int qc = 0; qc < 16; ++qc)
    S += psum[(b * 16 + qc) * T_ + k] * __expf(pmax[(b * 16 + qc) * T_ + k] - M);
  stats[2 * i] = M;
  stats[2 * i + 1] = 1.0f / S;
}

__global__ __launch_bounds__(256) void sm_pass3(const float* __restrict__ scores,
                                                const float* __restrict__ stats,
                                                unsigned short* __restrict__ wts) {
  int k = blockIdx.x * 256 + threadIdx.x;
  int qc = blockIdx.y, b = blockIdx.z;
  float M = stats[2 * (b * T_ + k)];
  float Sinv = stats[2 * (b * T_ + k) + 1];
  const float* S = scores + (size_t)b * T_ * T_ + (size_t)qc * 128 * T_ + k;
  unsigned short* W = wts + (size_t)b * T_ * T_ + (size_t)qc * 128 * T_ + k;
  #pragma unroll 4
  for (int q = 0; q < 128; ++q) {
    float v = S[(size_t)q * T_];
    W[(size_t)q * T_] = f2h(__expf(v - M) * Sinv);
  }
}

// --------------------------------------------------------------------
extern "C" void kernel_launch(void* const* d_in, const int* in_sizes, int n_in,
                              void* d_out, int out_size, void* d_ws, size_t ws_size,
                              hipStream_t stream) {
  const float* x  = (const float*)d_in[0];
  const float* Wq = (const float*)d_in[1];
  const float* Wk = (const float*)d_in[2];
  const float* Wv = (const float*)d_in[3];
  float* out = (float*)d_out;

  char* ws = (char*)d_ws;
  const size_t MB = 1024ull * 1024ull;
  float*          scores = (float*)(ws);                       // 64 MB
  unsigned short* QK   = (unsigned short*)(ws + 64 * MB);      // 32 MB [8192][2048]
  unsigned short* Vt   = (unsigned short*)(ws + 96 * MB);      // 16 MB [4][1024][2048]
  unsigned short* xh   = (unsigned short*)(ws + 112 * MB);     // 16 MB fp16 x
  unsigned short* Wt   = (unsigned short*)(ws + 128 * MB);     // 6 MB  [3072][1024]
  float* pmax  = (float*)(ws + 134 * MB);                      // 512 KB
  float* psum  = (float*)(ws + 134 * MB + 512 * 1024);         // 512 KB
  float* stats = (float*)(ws + 135 * MB);                      // 64 KB
  unsigned short* wts = (unsigned short*)(ws + 136 * MB);      // 32 MB fp16

  // 1. x -> fp16
  tofp16_kernel<<<MTOK * D_ / 4 / 256, 256, 0, stream>>>(
      (const float4*)x, (ushort4*)xh, MTOK * D_ / 4);

  // 2. transpose + concat W -> fp16
  wcat_t_kernel<<<dim3(32, 32, 3), 256, 0, stream>>>(Wq, Wk, Wv, Wt);

  // 3. fused QKV projection: C[8192][3072]; V stored transposed
  gemm8p<8, 1><<<dim3(3072 / 256, MTOK / 256, 1), 512, 0, stream>>>(
      xh, Wt, QK, Vt, D_, D_, D_, 0, 0, 0, 0);

  // 4. scores = Q K^T (fp16 in, fp32 out), per batch
  gemm8p<8, 0><<<dim3(T_ / 256, T_ / 256, B_), 512, 0, stream>>>(
      QK, QK + 1024, scores, nullptr, D_, 2048, 2048, T_,
      (long)T_ * 2048, (long)T_ * 2048, (long)T_ * T_);

  // 5. softmax over query axis -> fp16 weights
  sm_pass1<<<dim3(8, 16, 4), 256, 0, stream>>>(scores, pmax, psum);
  sm_pass2<<<32, 256, 0, stream>>>(pmax, psum, stats);
  sm_pass3<<<dim3(8, 16, 4), 256, 0, stream>>>(scores, stats, wts);

  // 6. out = weights @ V  (bt-form against Vt), BM=128 keeps 256 blocks
  gemm8p<4, 0><<<dim3(D_ / 256, T_ / 128, B_), 512, 0, stream>>>(
      wts, Vt, out, nullptr, T_, 2048, 2048, D_,
      (long)T_ * 2048, (long)D_ * T_, (long)T_ * D_);
}

// Round 5
// 208.617 us; speedup vs baseline: 1.9351x; 1.0890x over previous
//
#include <hip/hip_runtime.h>

#define B_   4
#define T_   2048
#define D_   1024
#define MTOK 8192  // B_*T_

typedef __attribute__((ext_vector_type(8))) _Float16 half8;
typedef __attribute__((ext_vector_type(4))) float    f32x4;

#define GLD(G, L) __builtin_amdgcn_global_load_lds(                       \
    (const __attribute__((address_space(1))) void*)(G),                   \
    (__attribute__((address_space(3))) void*)(L), 16, 0, 0)

#define BAR()   __builtin_amdgcn_s_barrier()
#define LGKM0() do { asm volatile("s_waitcnt lgkmcnt(0)" ::: "memory");   \
                     __builtin_amdgcn_sched_barrier(0); } while (0)
#define VMW8()  asm volatile("s_waitcnt vmcnt(8)" ::: "memory")
#define VMW6()  asm volatile("s_waitcnt vmcnt(6)" ::: "memory")
#define VMW0()  asm volatile("s_waitcnt vmcnt(0)" ::: "memory")

__device__ __forceinline__ unsigned short f2h(float f) {
  return __builtin_bit_cast(unsigned short, (_Float16)f);  // RTE
}

// ---------------- prep: x fp32 -> fp16 ------------------------------
__global__ __launch_bounds__(256) void tofp16_kernel(
    const float4* __restrict__ in, ushort4* __restrict__ out, int n4) {
  int i = blockIdx.x * 256 + threadIdx.x;
  if (i >= n4) return;
  float4 v = in[i];
  ushort4 h;
  h.x = f2h(v.x); h.y = f2h(v.y); h.z = f2h(v.z); h.w = f2h(v.w);
  out[i] = h;
}

// ---------------- prep: transpose + concat W -> fp16 ----------------
__global__ __launch_bounds__(256) void wcat_t_kernel(
    const float* __restrict__ Wq, const float* __restrict__ Wk,
    const float* __restrict__ Wv, unsigned short* __restrict__ Wt) {
  __shared__ float tile[32][33];
  int z = blockIdx.z;
  const float* W = (z == 0) ? Wq : ((z == 1) ? Wk : Wv);
  int c0 = blockIdx.x * 32, r0 = blockIdx.y * 32;
  int tx = threadIdx.x & 31, ty = threadIdx.x >> 5;  // 32 x 8
  #pragma unroll
  for (int i = 0; i < 4; ++i)
    tile[ty + i * 8][tx] = W[(size_t)(r0 + ty + i * 8) * D_ + c0 + tx];
  __syncthreads();
  #pragma unroll
  for (int i = 0; i < 4; ++i) {
    float v = tile[tx][ty + i * 8];
    size_t row = (size_t)z * D_ + c0 + ty + i * 8;
    Wt[row * D_ + r0 + tx] = f2h(v);
  }
}

// ---------------- V transpose: QKV cols [2048,3072) -> Vt[b][d][t] --
__global__ __launch_bounds__(256) void vtrans_kernel(
    const unsigned short* __restrict__ QKV, unsigned short* __restrict__ Vt) {
  __shared__ unsigned short tile[64][68];  // pad 4 ushort: 136B stride, 8B-aligned
  int b = blockIdx.z;
  int t0 = blockIdx.x * 64, d0 = blockIdx.y * 64;
  int l16 = threadIdx.x & 15, rr = threadIdx.x >> 4;
  const unsigned short* src =
      QKV + ((size_t)b * 2048 + t0 + rr) * 3072 + 2048 + d0 + l16 * 4;
  #pragma unroll
  for (int i = 0; i < 4; ++i) {
    ushort4 v = *(const ushort4*)(src + (size_t)i * 16 * 3072);
    *(ushort4*)&tile[rr + i * 16][l16 * 4] = v;
  }
  __syncthreads();
  unsigned short* dst = Vt + ((size_t)b * D_ + d0) * 2048 + t0;
  #pragma unroll
  for (int j = 0; j < 4; ++j) {
    int dd = rr + j * 16;     // d-row of output
    int tt = l16 * 4;         // 4 consecutive t per lane
    ushort4 v;
    v.x = tile[tt + 0][dd]; v.y = tile[tt + 1][dd];
    v.z = tile[tt + 2][dd]; v.w = tile[tt + 3][dd];
    *(ushort4*)(dst + (size_t)dd * 2048 + tt) = v;
  }
}

// ---------------- 8-phase pipelined GEMM (bt-form, fp16) ------------
// C[m][n] = sum_k A[m][k] * B[n][k].  BM = FM*32 (256 or 128), BN = 256,
// BK = 64, 512 threads = 8 waves (2M x 4N).  LDS: 2 K-tile buffers,
// XOR-swizzled 16B slots (slot ^= row&7).  4 phases per K-tile; freed
// regions restaged next phase; counted vmcnt at K-tile end only.
// EPI: 0 = fp32 store; 1 = fp16 row-major store (ldc)
template <int FM, int EPI>
__global__ __launch_bounds__(512) void gemm8p(
    const unsigned short* __restrict__ A, const unsigned short* __restrict__ B,
    void* __restrict__ C0,
    int K, int lda, int ldb, int ldc,
    long aBatch, long bBatch, long cBatch) {
  constexpr int BM   = FM * 32;
  constexpr int ABY  = BM * 128;        // A bytes per buffer
  constexpr int BUFB = ABY + 32768;     // bytes per K-tile buffer
  __shared__ __align__(16) char lds[2 * BUFB];

  const int z = blockIdx.z;
  A += (size_t)z * aBatch;
  B += (size_t)z * bBatch;

  // XCD-bijective swizzle (all grids have nwg % 8 == 0)
  const int nwg = gridDim.x * gridDim.y;
  int s = blockIdx.y * gridDim.x + blockIdx.x;
  s = (s & 7) * (nwg >> 3) + (s >> 3);
  const int bx = s % gridDim.x, by = s / gridDim.x;
  const int brow = by * BM, bcol = bx * 256;

  const int tid = threadIdx.x;
  const int wid = tid >> 6, lane = tid & 63;
  const int wr = wid >> 2, wc = wid & 3;
  const int l15 = lane & 15, l7 = lane & 7, g4 = lane >> 4, lr8 = lane >> 3;

  // ---- staging geometry (write side: linear LDS, inverse-swz source) ----
  const int scol = (l7 ^ lr8) * 8;  // swizzled 16B k-slot in global source
  int aoffs[2][2], adst[2][2], boffs[2][2], bdst[2][2];
  #pragma unroll
  for (int rg = 0; rg < 2; ++rg)
    #pragma unroll
    for (int j = 0; j < 2; ++j) {
      int r0;
      if constexpr (FM == 8) r0 = rg * 64 + j * 128 + wid * 8;
      else                   r0 = (wid >> 2) * 64 + rg * 32 + (wid & 3) * 8;
      aoffs[rg][j] = (brow + r0 + lr8) * lda + scol;
      adst[rg][j]  = r0 * 128;
      int g16 = j * 8 + wid;
      int rb  = (g16 >> 2) * 64 + rg * 32 + (g16 & 3) * 8;
      boffs[rg][j] = (bcol + rb + lr8) * ldb + scol;
      bdst[rg][j]  = ABY + rb * 128;
    }

  // ---- read geometry (swizzled ds_read_b128 bases) ----
  int aRd[2][2], bRd[2][2];
  #pragma unroll
  for (int mh = 0; mh < 2; ++mh)
    #pragma unroll
    for (int ks = 0; ks < 2; ++ks) {
      int arow = wr * (BM / 2) + mh * (BM / 4) + l15;
      int bcolr = wc * 64 + mh * 32 + l15;   // mh doubles as nh
      int ph = ((ks * 4) + g4) ^ l7;
      aRd[mh][ks] = arow * 128 + ph * 16;
      bRd[mh][ks] = ABY + bcolr * 128 + ph * 16;
    }

#define STAGE_A(rg, bb, tt) do {                                              \
    GLD(A + (size_t)(aoffs[rg][0] + (tt) * 64), lds + (bb) * BUFB + adst[rg][0]); \
    if constexpr (FM == 8)                                                    \
      GLD(A + (size_t)(aoffs[rg][1] + (tt) * 64), lds + (bb) * BUFB + adst[rg][1]); \
  } while (0)
#define STAGE_B(nh, bb, tt) do {                                              \
    GLD(B + (size_t)(boffs[nh][0] + (tt) * 64), lds + (bb) * BUFB + bdst[nh][0]); \
    GLD(B + (size_t)(boffs[nh][1] + (tt) * 64), lds + (bb) * BUFB + bdst[nh][1]); \
  } while (0)
#define LOAD_A(mh) do { _Pragma("unroll")                                     \
    for (int mf = 0; mf < FM / 2; ++mf) {                                     \
      ar[mf][0] = *(const half8*)(buf + aRd[mh][0] + mf * 2048);              \
      ar[mf][1] = *(const half8*)(buf + aRd[mh][1] + mf * 2048); } } while (0)
#define LOAD_B(dst, nh) do { _Pragma("unroll")                                \
    for (int nf = 0; nf < 2; ++nf) {                                          \
      dst[nf][0] = *(const half8*)(buf + bRd[nh][0] + nf * 2048);             \
      dst[nf][1] = *(const half8*)(buf + bRd[nh][1] + nf * 2048); } } while (0)
#define MFMA_Q(mh, nh, br) do { _Pragma("unroll")                             \
    for (int mf = 0; mf < FM / 2; ++mf) { _Pragma("unroll")                   \
      for (int nf = 0; nf < 2; ++nf) {                                        \
        f32x4& ac = acc[(mh) * (FM / 2) + mf][(nh) * 2 + nf];                 \
        ac = __builtin_amdgcn_mfma_f32_16x16x32_f16(ar[mf][0], br[nf][0], ac, 0, 0, 0); \
        ac = __builtin_amdgcn_mfma_f32_16x16x32_f16(ar[mf][1], br[nf][1], ac, 0, 0, 0); \
      } } } while (0)
#define VMCNT_STEADY() do { if (st) { if constexpr (FM == 8) VMW8(); else VMW6(); } \
                            else VMW0(); } while (0)

  // ---- prologue: stage K-tiles 0 (buf0) and 1 (buf1) ----
  STAGE_A(0, 0, 0); STAGE_B(0, 0, 0); STAGE_B(1, 0, 0); STAGE_A(1, 0, 0);
  STAGE_A(0, 1, 1); STAGE_B(0, 1, 1); STAGE_B(1, 1, 1); STAGE_A(1, 1, 1);
  if constexpr (FM == 8) VMW8(); else VMW6();
  BAR();

  f32x4 acc[FM][4] = {};
  half8 ar[FM / 2][2], b0r[2][2], b1r[2][2];
  const int nIter = K / 128;

  for (int it = 0; it < nIter; ++it) {
    const bool st = (it + 1 < nIter);
    #pragma unroll
    for (int h = 0; h < 2; ++h) {
      const char* buf = lds + h * BUFB;
      const int tt = 2 * it + 2 + h;
      // phase 1: read A-mh0 + B-nh0
      LOAD_A(0); LOAD_B(b0r, 0);
      BAR(); LGKM0();
      __builtin_amdgcn_s_setprio(1); MFMA_Q(0, 0, b0r);
      __builtin_amdgcn_s_setprio(0); BAR();
      // phase 2: read B-nh1; stage A0 + B0 regions (freed in phase 1)
      LOAD_B(b1r, 1);
      if (st) { STAGE_A(0, h, tt); STAGE_B(0, h, tt); }
      BAR(); LGKM0();
      __builtin_amdgcn_s_setprio(1); MFMA_Q(0, 1, b1r);
      __builtin_amdgcn_s_setprio(0); BAR();
      // phase 3: read A-mh1; stage B1 region (freed in phase 2)
      LOAD_A(1);
      if (st) STAGE_B(1, h, tt);
      BAR(); LGKM0();
      __builtin_amdgcn_s_setprio(1); MFMA_Q(1, 1, b1r);
      __builtin_amdgcn_s_setprio(0); BAR();
      // phase 4: stage A1 region (freed in phase 3); counted vmcnt
      if (st) STAGE_A(1, h, tt);
      BAR();
      __builtin_amdgcn_s_setprio(1); MFMA_Q(1, 0, b0r);
      __builtin_amdgcn_s_setprio(0);
      VMCNT_STEADY(); BAR();
    }
  }

  // ---- epilogue ----
  #pragma unroll
  for (int m = 0; m < FM; ++m) {
    int rowoff;
    if constexpr (FM == 8) rowoff = (m >> 2) * 64 + (m & 3) * 16;
    else                   rowoff = (m >> 1) * 32 + (m & 1) * 16;
    #pragma unroll
    for (int n = 0; n < 4; ++n) {
      int coloff = (n >> 1) * 32 + (n & 1) * 16;
      #pragma unroll
      for (int r = 0; r < 4; ++r) {
        int row = brow + wr * (BM / 2) + rowoff + g4 * 4 + r;
        int col = bcol + wc * 64 + coloff + l15;
        float v = acc[m][n][r];
        if constexpr (EPI == 0) {
          float* C = (float*)C0 + (size_t)z * cBatch;
          C[(size_t)row * ldc + col] = v;
        } else {
          ((unsigned short*)C0)[(size_t)row * ldc + col] = f2h(v);
        }
      }
    }
  }
#undef STAGE_A
#undef STAGE_B
#undef LOAD_A
#undef LOAD_B
#undef MFMA_Q
#undef VMCNT_STEADY
}

// ------- softmax over QUERY axis, fixed-shift form (shift cancels) --
__global__ __launch_bounds__(256) void sm_sum(const float* __restrict__ scores,
                                              float* __restrict__ psum) {
  int k = blockIdx.x * 256 + threadIdx.x;
  int qc = blockIdx.y, b = blockIdx.z;
  const float* S = scores + (size_t)b * T_ * T_ + (size_t)qc * 128 * T_ + k;
  float s = 0.f;
  #pragma unroll 4
  for (int q = 0; q < 128; ++q) s += __expf(S[(size_t)q * T_] - 64.0f);
  psum[(b * 16 + qc) * T_ + k] = s;
}

__global__ __launch_bounds__(256) void sm_stats(const float* __restrict__ psum,
                                                float* __restrict__ stats) {
  int i = blockIdx.x * 256 + threadIdx.x;  // b*2048 + k
  int b = i >> 11, k = i & 2047;
  float S = 0.f;
  #pragma unroll
  for (int qc = 0; qc < 16; ++qc) S += psum[(b * 16 + qc) * T_ + k];
  stats[i] = 1.0f / S;
}

__global__ __launch_bounds__(256) void sm_apply(const float* __restrict__ scores,
                                                const float* __restrict__ stats,
                                                unsigned short* __restrict__ wts) {
  int k = blockIdx.x * 256 + threadIdx.x;
  int qc = blockIdx.y, b = blockIdx.z;
  float Sinv = stats[b * T_ + k];
  const float* S = scores + (size_t)b * T_ * T_ + (size_t)qc * 128 * T_ + k;
  unsigned short* W = wts + (size_t)b * T_ * T_ + (size_t)qc * 128 * T_ + k;
  #pragma unroll 4
  for (int q = 0; q < 128; ++q) {
    float v = S[(size_t)q * T_];
    W[(size_t)q * T_] = f2h(__expf(v - 64.0f) * Sinv);
  }
}

// --------------------------------------------------------------------
extern "C" void kernel_launch(void* const* d_in, const int* in_sizes, int n_in,
                              void* d_out, int out_size, void* d_ws, size_t ws_size,
                              hipStream_t stream) {
  const float* x  = (const float*)d_in[0];
  const float* Wq = (const float*)d_in[1];
  const float* Wk = (const float*)d_in[2];
  const float* Wv = (const float*)d_in[3];
  float* out = (float*)d_out;

  char* ws = (char*)d_ws;
  const size_t MB = 1024ull * 1024ull;
  float*          scores = (float*)(ws);                       // 64 MB
  unsigned short* QKVh = (unsigned short*)(ws + 64 * MB);      // 48 MB [8192][3072]
  unsigned short* Vt   = (unsigned short*)(ws + 112 * MB);     // 16 MB [4][1024][2048]
  unsigned short* xh   = (unsigned short*)(ws + 128 * MB);     // 16 MB fp16 x
  unsigned short* Wt   = (unsigned short*)(ws + 144 * MB);     // 6 MB  [3072][1024]
  float* psum  = (float*)(ws + 150 * MB);                      // 512 KB
  float* stats = (float*)(ws + 150 * MB + 512 * 1024);         // 32 KB
  unsigned short* wts = (unsigned short*)(ws + 151 * MB);      // 32 MB fp16

  // 1. x -> fp16
  tofp16_kernel<<<MTOK * D_ / 4 / 256, 256, 0, stream>>>(
      (const float4*)x, (ushort4*)xh, MTOK * D_ / 4);

  // 2. transpose + concat W -> fp16
  wcat_t_kernel<<<dim3(32, 32, 3), 256, 0, stream>>>(Wq, Wk, Wv, Wt);

  // 3. fused QKV projection: natural fp16 store C[8192][3072]
  gemm8p<8, 1><<<dim3(3072 / 256, MTOK / 256, 1), 512, 0, stream>>>(
      xh, Wt, QKVh, D_, D_, D_, 3072, 0, 0, 0);

  // 4. V transpose -> Vt[b][d][t]
  vtrans_kernel<<<dim3(T_ / 64, D_ / 64, B_), 256, 0, stream>>>(QKVh, Vt);

  // 5. scores = Q K^T (fp16 in, fp32 out), per batch
  gemm8p<8, 0><<<dim3(T_ / 256, T_ / 256, B_), 512, 0, stream>>>(
      QKVh, QKVh + 1024, scores, D_, 3072, 3072, T_,
      (long)T_ * 3072, (long)T_ * 3072, (long)T_ * T_);

  // 6. softmax over query axis -> fp16 weights
  sm_sum<<<dim3(8, 16, 4), 256, 0, stream>>>(scores, psum);
  sm_stats<<<32, 256, 0, stream>>>(psum, stats);
  sm_apply<<<dim3(8, 16, 4), 256, 0, stream>>>(scores, stats, wts);

  // 7. out = weights @ V  (bt-form against Vt), BM=128 for grid balance
  gemm8p<4, 0><<<dim3(D_ / 256, T_ / 128, B_), 512, 0, stream>>>(
      wts, Vt, out, T_, 2048, 2048, D_,
      (long)T_ * 2048, (long)D_ * T_, (long)T_ * D_);
}

// Round 7
// 208.536 us; speedup vs baseline: 1.9358x; 1.0004x over previous
//
#include <hip/hip_runtime.h>

#define B_   4
#define T_   2048
#define D_   1024
#define MTOK 8192  // B_*T_

typedef __attribute__((ext_vector_type(8))) _Float16 half8;
typedef __attribute__((ext_vector_type(4))) float    f32x4;

#define GLD(G, L) __builtin_amdgcn_global_load_lds(                       \
    (const __attribute__((address_space(1))) void*)(G),                   \
    (__attribute__((address_space(3))) void*)(L), 16, 0, 0)

#define BAR()   __builtin_amdgcn_s_barrier()
#define LGKM0() do { asm volatile("s_waitcnt lgkmcnt(0)" ::: "memory");   \
                     __builtin_amdgcn_sched_barrier(0); } while (0)
#define VMW4()  asm volatile("s_waitcnt vmcnt(4)" ::: "memory")
#define VMW3()  asm volatile("s_waitcnt vmcnt(3)" ::: "memory")
#define VMW0()  asm volatile("s_waitcnt vmcnt(0)" ::: "memory")

__device__ __forceinline__ unsigned short f2h(float f) {
  return __builtin_bit_cast(unsigned short, (_Float16)f);  // RTE
}
__device__ __forceinline__ float h2f(unsigned short u) {
  return (float)__builtin_bit_cast(_Float16, u);
}

// ---------------- prep: x fp32 -> fp16 ------------------------------
__global__ __launch_bounds__(256) void tofp16_kernel(
    const float4* __restrict__ in, ushort4* __restrict__ out, int n4) {
  int i = blockIdx.x * 256 + threadIdx.x;
  if (i >= n4) return;
  float4 v = in[i];
  ushort4 h;
  h.x = f2h(v.x); h.y = f2h(v.y); h.z = f2h(v.z); h.w = f2h(v.w);
  out[i] = h;
}

// ---------------- prep: transpose + concat W -> fp16 ----------------
__global__ __launch_bounds__(256) void wcat_t_kernel(
    const float* __restrict__ Wq, const float* __restrict__ Wk,
    const float* __restrict__ Wv, unsigned short* __restrict__ Wt) {
  __shared__ float tile[32][33];
  int z = blockIdx.z;
  const float* W = (z == 0) ? Wq : ((z == 1) ? Wk : Wv);
  int c0 = blockIdx.x * 32, r0 = blockIdx.y * 32;
  int tx = threadIdx.x & 31, ty = threadIdx.x >> 5;  // 32 x 8
  #pragma unroll
  for (int i = 0; i < 4; ++i)
    tile[ty + i * 8][tx] = W[(size_t)(r0 + ty + i * 8) * D_ + c0 + tx];
  __syncthreads();
  #pragma unroll
  for (int i = 0; i < 4; ++i) {
    float v = tile[tx][ty + i * 8];
    size_t row = (size_t)z * D_ + c0 + ty + i * 8;
    Wt[row * D_ + r0 + tx] = f2h(v);
  }
}

// ---------------- V transpose: QKV cols [2048,3072) -> Vt[b][d][t] --
__global__ __launch_bounds__(256) void vtrans_kernel(
    const unsigned short* __restrict__ QKV, unsigned short* __restrict__ Vt) {
  __shared__ unsigned short tile[64][68];
  int b = blockIdx.z;
  int t0 = blockIdx.x * 64, d0 = blockIdx.y * 64;
  int l16 = threadIdx.x & 15, rr = threadIdx.x >> 4;
  const unsigned short* src =
      QKV + ((size_t)b * 2048 + t0 + rr) * 3072 + 2048 + d0 + l16 * 4;
  #pragma unroll
  for (int i = 0; i < 4; ++i) {
    ushort4 v = *(const ushort4*)(src + (size_t)i * 16 * 3072);
    *(ushort4*)&tile[rr + i * 16][l16 * 4] = v;
  }
  __syncthreads();
  unsigned short* dst = Vt + ((size_t)b * D_ + d0) * 2048 + t0;
  #pragma unroll
  for (int j = 0; j < 4; ++j) {
    int dd = rr + j * 16;
    int tt = l16 * 4;
    ushort4 v;
    v.x = tile[tt + 0][dd]; v.y = tile[tt + 1][dd];
    v.z = tile[tt + 2][dd]; v.w = tile[tt + 3][dd];
    *(ushort4*)(dst + (size_t)dd * 2048 + tt) = v;
  }
}

// ---------------- 8-phase pipelined GEMM, BK=32 (bt-form, fp16) -----
// C[m][n] = sum_k A[m][k] * B[n][k].  BM = FM*32 (256 or 128), BN = 256,
// BK = 32 (64 B/row = 4 x 16B slots), 512 threads = 8 waves (2M x 4N).
// LDS: 2 K-tile buffers (FM=8: 64 KB -> 2 blocks/CU; FM=4: 48 KB -> 3).
// Swizzle: phys slot = logical ^ ((row>>1)&3); write side pre-applies the
// inverse permutation on the global source (rule #21).
// INVARIANT (round-6 bugfix): each phase restages EXACTLY the union over
// all waves of the region read in the previous phase:
//   A-mh region = rows { wr*BM/2 + mh*BM/4 .. +BM/4 } over wr
//   B-nh region = rows { wc*64 + nh*32 .. +32 }       over wc
// Counted vmcnt(4/3) once per K-tile; stages during tile t feed tile t+2.
// EPI: 0 = fp32 store; 1 = fp16 row-major store
template <int FM, int EPI>
__global__ __launch_bounds__(512) void gemm8p(
    const unsigned short* __restrict__ A, const unsigned short* __restrict__ B,
    void* __restrict__ C0,
    int K, int lda, int ldb, int ldc,
    long aBatch, long bBatch, long cBatch) {
  constexpr int BM   = FM * 32;
  constexpr int ABY  = BM * 64;         // A bytes per buffer (64 B per row)
  constexpr int BUFB = ABY + 16384;     // + B: 256 rows * 64 B
  __shared__ __align__(16) char lds[2 * BUFB];

  const int z = blockIdx.z;
  A += (size_t)z * aBatch;
  B += (size_t)z * bBatch;

  // XCD-bijective swizzle (all grids have nwg % 8 == 0)
  const int nwg = gridDim.x * gridDim.y;
  int s = blockIdx.y * gridDim.x + blockIdx.x;
  s = (s & 7) * (nwg >> 3) + (s >> 3);
  const int bx = s % gridDim.x, by = s / gridDim.x;
  const int brow = by * BM, bcol = bx * 256;

  const int tid = threadIdx.x;
  const int wid = tid >> 6, lane = tid & 63;
  const int wr = wid >> 2, wc = wid & 3;
  const int l15 = lane & 15, g4 = lane >> 4;

  // ---- staging geometry: GLD line = 16 rows x 64 B; lane l -> row l>>2,
  //      phys slot l&3; source slot = (l&3) ^ ((l>>3)&3) (16-row bases).
  const int scol = ((lane & 3) ^ ((lane >> 3) & 3)) * 8;
  const int srow = lane >> 2;
  int aoffs[2], adst[2], boffs[2], bdst[2];
  #pragma unroll
  for (int rg = 0; rg < 2; ++rg) {
    int r0;
    if constexpr (FM == 8)
      r0 = (wid >> 2) * 128 + rg * 64 + (wid & 3) * 16;  // == A-mh{rg} union
    else
      r0 = wid * 16;  // FM=4: whole A in one call, staged in phase 4 only
    aoffs[rg] = (brow + r0 + srow) * lda + scol;
    adst[rg]  = r0 * 64;
    int rb = (wid >> 1) * 64 + rg * 32 + (wid & 1) * 16; // == B-nh{rg} union
    boffs[rg] = (bcol + rb + srow) * ldb + scol;
    bdst[rg]  = ABY + rb * 64;
  }

  // ---- read geometry: one b128 per 16x16x32 A/B fragment ----
  const int rslot = (g4 ^ ((l15 >> 1) & 3)) * 16;
  int aRd[2], bRd[2];
  #pragma unroll
  for (int mh = 0; mh < 2; ++mh) {
    aRd[mh] = (wr * (BM / 2) + mh * (BM / 4) + l15) * 64 + rslot;
    bRd[mh] = ABY + (wc * 64 + mh * 32 + l15) * 64 + rslot;
  }

#define STAGE_A(rg, bb, tt) \
    GLD(A + (size_t)(aoffs[rg] + (tt) * 32), lds + (bb) * BUFB + adst[rg])
#define STAGE_B(nh, bb, tt) \
    GLD(B + (size_t)(boffs[nh] + (tt) * 32), lds + (bb) * BUFB + bdst[nh])
#define LOAD_A(mh) do { _Pragma("unroll")                                     \
    for (int mf = 0; mf < FM / 2; ++mf)                                       \
      ar[mf] = *(const half8*)(buf + aRd[mh] + mf * 1024); } while (0)
#define LOAD_B(dst, nh) do { _Pragma("unroll")                                \
    for (int nf = 0; nf < 2; ++nf)                                            \
      dst[nf] = *(const half8*)(buf + bRd[nh] + nf * 1024); } while (0)
#define MFMA_Q(mh, nh, br) do { _Pragma("unroll")                             \
    for (int mf = 0; mf < FM / 2; ++mf) { _Pragma("unroll")                   \
      for (int nf = 0; nf < 2; ++nf) {                                        \
        f32x4& ac = acc[(mh) * (FM / 2) + mf][(nh) * 2 + nf];                 \
        ac = __builtin_amdgcn_mfma_f32_16x16x32_f16(ar[mf], br[nf], ac, 0, 0, 0); \
      } } } while (0)
#define VMW_ST() do { if constexpr (FM == 8) VMW4(); else VMW3(); } while (0)

  // ---- prologue: stage K-tiles 0 (buf0) and 1 (buf1) ----
  if constexpr (FM == 8) {
    STAGE_A(0, 0, 0); STAGE_B(0, 0, 0); STAGE_B(1, 0, 0); STAGE_A(1, 0, 0);
    STAGE_A(0, 1, 1); STAGE_B(0, 1, 1); STAGE_B(1, 1, 1); STAGE_A(1, 1, 1);
  } else {
    STAGE_A(0, 0, 0); STAGE_B(0, 0, 0); STAGE_B(1, 0, 0);
    STAGE_A(0, 1, 1); STAGE_B(0, 1, 1); STAGE_B(1, 1, 1);
  }
  VMW_ST();  // buf0 complete (FIFO), buf1 may remain in flight
  BAR();

  f32x4 acc[FM][4] = {};
  half8 ar[FM / 2], b0r[2], b1r[2];
  const int nIter = K / 64;

  for (int it = 0; it < nIter; ++it) {
    const bool st = (it + 1 < nIter);
    #pragma unroll
    for (int h = 0; h < 2; ++h) {
      const char* buf = lds + h * BUFB;
      const int tt = 2 * it + 2 + h;
      // phase 1: read A-mh0 + B-nh0
      LOAD_A(0); LOAD_B(b0r, 0);
      BAR(); LGKM0();
      __builtin_amdgcn_s_setprio(1); MFMA_Q(0, 0, b0r);
      __builtin_amdgcn_s_setprio(0); BAR();
      // phase 2: read B-nh1; restage A-mh0 + B-nh0 regions (freed phase 1)
      LOAD_B(b1r, 1);
      if (st) {
        if constexpr (FM == 8) STAGE_A(0, h, tt);
        STAGE_B(0, h, tt);
      }
      BAR(); LGKM0();
      __builtin_amdgcn_s_setprio(1); MFMA_Q(0, 1, b1r);
      __builtin_amdgcn_s_setprio(0); BAR();
      // phase 3: read A-mh1; restage B-nh1 region (freed phase 2)
      LOAD_A(1);
      if (st) STAGE_B(1, h, tt);
      BAR(); LGKM0();
      __builtin_amdgcn_s_setprio(1); MFMA_Q(1, 1, b1r);
      __builtin_amdgcn_s_setprio(0); BAR();
      // phase 4: restage A-mh1 (FM=4: whole A; freed after phase 3)
      if (st) {
        if constexpr (FM == 8) STAGE_A(1, h, tt);
        else                   STAGE_A(0, h, tt);
      }
      BAR();
      __builtin_amdgcn_s_setprio(1); MFMA_Q(1, 0, b0r);
      __builtin_amdgcn_s_setprio(0);
      if (st) { VMW_ST(); } else { VMW0(); }
      BAR();
    }
  }

  // ---- epilogue ----
  #pragma unroll
  for (int m = 0; m < FM; ++m) {
    int rowoff;
    if constexpr (FM == 8) rowoff = (m >> 2) * 64 + (m & 3) * 16;
    else                   rowoff = (m >> 1) * 32 + (m & 1) * 16;
    #pragma unroll
    for (int n = 0; n < 4; ++n) {
      int coloff = (n >> 1) * 32 + (n & 1) * 16;
      #pragma unroll
      for (int r = 0; r < 4; ++r) {
        int row = brow + wr * (BM / 2) + rowoff + g4 * 4 + r;
        int col = bcol + wc * 64 + coloff + l15;
        float v = acc[m][n][r];
        if constexpr (EPI == 0) {
          float* C = (float*)C0 + (size_t)z * cBatch;
          C[(size_t)row * ldc + col] = v;
        } else {
          unsigned short* C = (unsigned short*)C0 + (size_t)z * cBatch;
          C[(size_t)row * ldc + col] = f2h(v);
        }
      }
    }
  }
#undef STAGE_A
#undef STAGE_B
#undef LOAD_A
#undef LOAD_B
#undef MFMA_Q
#undef VMW_ST
}

// ------- softmax over QUERY axis, fixed-shift form (fp16 scores) ----
__global__ __launch_bounds__(256) void sm_sum(const unsigned short* __restrict__ scores,
                                              float* __restrict__ psum) {
  int k = blockIdx.x * 256 + threadIdx.x;
  int qc = blockIdx.y, b = blockIdx.z;
  const unsigned short* S = scores + (size_t)b * T_ * T_ + (size_t)qc * 128 * T_ + k;
  float s = 0.f;
  #pragma unroll 4
  for (int q = 0; q < 128; ++q) s += __expf(h2f(S[(size_t)q * T_]) - 64.0f);
  psum[(b * 16 + qc) * T_ + k] = s;
}

__global__ __launch_bounds__(256) void sm_stats(const float* __restrict__ psum,
                                                float* __restrict__ stats) {
  int i = blockIdx.x * 256 + threadIdx.x;  // b*2048 + k
  int b = i >> 11, k = i & 2047;
  float S = 0.f;
  #pragma unroll
  for (int qc = 0; qc < 16; ++qc) S += psum[(b * 16 + qc) * T_ + k];
  stats[i] = 1.0f / S;
}

__global__ __launch_bounds__(256) void sm_apply(const unsigned short* __restrict__ scores,
                                                const float* __restrict__ stats,
                                                unsigned short* __restrict__ wts) {
  int k = blockIdx.x * 256 + threadIdx.x;
  int qc = blockIdx.y, b = blockIdx.z;
  float Sinv = stats[b * T_ + k];
  const unsigned short* S = scores + (size_t)b * T_ * T_ + (size_t)qc * 128 * T_ + k;
  unsigned short* W = wts + (size_t)b * T_ * T_ + (size_t)qc * 128 * T_ + k;
  #pragma unroll 4
  for (int q = 0; q < 128; ++q) {
    float v = h2f(S[(size_t)q * T_]);
    W[(size_t)q * T_] = f2h(__expf(v - 64.0f) * Sinv);
  }
}

// --------------------------------------------------------------------
extern "C" void kernel_launch(void* const* d_in, const int* in_sizes, int n_in,
                              void* d_out, int out_size, void* d_ws, size_t ws_size,
                              hipStream_t stream) {
  const float* x  = (const float*)d_in[0];
  const float* Wq = (const float*)d_in[1];
  const float* Wk = (const float*)d_in[2];
  const float* Wv = (const float*)d_in[3];
  float* out = (float*)d_out;

  char* ws = (char*)d_ws;
  const size_t MB = 1024ull * 1024ull;
  unsigned short* scoresh = (unsigned short*)(ws);             // 32 MB fp16
  unsigned short* QKVh = (unsigned short*)(ws + 32 * MB);      // 48 MB [8192][3072]
  unsigned short* Vt   = (unsigned short*)(ws + 80 * MB);      // 16 MB [4][1024][2048]
  unsigned short* xh   = (unsigned short*)(ws + 96 * MB);      // 16 MB fp16 x
  unsigned short* Wt   = (unsigned short*)(ws + 112 * MB);     // 6 MB  [3072][1024]
  float* psum  = (float*)(ws + 118 * MB);                      // 512 KB
  float* stats = (float*)(ws + 118 * MB + 512 * 1024);         // 32 KB
  unsigned short* wts = (unsigned short*)(ws + 119 * MB);      // 32 MB fp16

  // 1. x -> fp16
  tofp16_kernel<<<MTOK * D_ / 4 / 256, 256, 0, stream>>>(
      (const float4*)x, (ushort4*)xh, MTOK * D_ / 4);

  // 2. transpose + concat W -> fp16
  wcat_t_kernel<<<dim3(32, 32, 3), 256, 0, stream>>>(Wq, Wk, Wv, Wt);

  // 3. fused QKV projection: natural fp16 store C[8192][3072]
  gemm8p<8, 1><<<dim3(3072 / 256, MTOK / 256, 1), 512, 0, stream>>>(
      xh, Wt, QKVh, D_, D_, D_, 3072, 0, 0, 0);

  // 4. V transpose -> Vt[b][d][t]
  vtrans_kernel<<<dim3(T_ / 64, D_ / 64, B_), 256, 0, stream>>>(QKVh, Vt);

  // 5. scores = Q K^T (fp16 in, fp16 out), per batch
  gemm8p<8, 1><<<dim3(T_ / 256, T_ / 256, B_), 512, 0, stream>>>(
      QKVh, QKVh + 1024, scoresh, D_, 3072, 3072, T_,
      (long)T_ * 3072, (long)T_ * 3072, (long)T_ * T_);

  // 6. softmax over query axis -> fp16 weights
  sm_sum<<<dim3(8, 16, 4), 256, 0, stream>>>(scoresh, psum);
  sm_stats<<<32, 256, 0, stream>>>(psum, stats);
  sm_apply<<<dim3(8, 16, 4), 256, 0, stream>>>(scoresh, stats, wts);

  // 7. out = weights @ V  (bt-form against Vt), FM=4 for grid balance
  gemm8p<4, 0><<<dim3(D_ / 256, T_ / 128, B_), 512, 0, stream>>>(
      wts, Vt, out, T_, 2048, 2048, D_,
      (long)T_ * 2048, (long)D_ * T_, (long)T_ * D_);
}